// Round 2
// baseline (895.179 us; speedup 1.0000x reference)
//
#include <hip/hip_runtime.h>
#include <stdint.h>

// LightMetaPolicy fused kernel, round 2: f32 I/O (reference dtype), f32 math,
// bf16 only for LDS-staged intermediates (E, MLP weights) to save LDS.
//
// Algebraic folds:
//   R = (x@Wq^T+bq)@Wr^T+br  ==  x@(Wr@Wq)^T + (Wr@bq+br)   -> fold into Wcat
//   pooled = sum_k (sum_q mask_q * A[q,k]) * V[k] / (summask+1e-8)
//
// Wcat rows (160 x 64, f32 in ws): [0:32)=Wq, [32:64)=Wk, [64:96)=Wr', [96:160)=Wv
// E LDS layout per agent-row: cols [0:32)=Q, [32:64)=K, [64:96)=R, [96:160)=V

#define ESTR 162   // E leading-dim pad: 81 dwords (odd) -> conflict-free over rows

__device__ __forceinline__ float b2f_lo(unsigned int pk) {
  union { unsigned int i; float f; } v; v.i = pk << 16; return v.f;
}
__device__ __forceinline__ float b2f_hi(unsigned int pk) {
  union { unsigned int i; float f; } v; v.i = pk & 0xffff0000u; return v.f;
}
__device__ __forceinline__ float b2f(unsigned short u) {
  union { unsigned int i; float f; } v; v.i = ((unsigned int)u) << 16; return v.f;
}
__device__ __forceinline__ unsigned short f2b(float f) {
  union { float f; unsigned int i; } v; v.f = f;
  unsigned int u = v.i;
  return (unsigned short)((u + 0x7fffu + ((u >> 16) & 1u)) >> 16);  // RNE
}

// ---------------------------------------------------------------- setup ----
__global__ void setup_kernel(const float* __restrict__ Wk,
                             const float* __restrict__ bk,
                             const float* __restrict__ Wq,
                             const float* __restrict__ bq,
                             const float* __restrict__ Wv,
                             const float* __restrict__ bv,
                             const float* __restrict__ Wr,
                             const float* __restrict__ br,
                             float* __restrict__ Wcat,
                             float* __restrict__ bcat) {
  int t = threadIdx.x;
  for (int i = t; i < 160 * 64; i += 256) {
    int r = i >> 6, d = i & 63;
    float v;
    if (r < 32) {
      v = Wq[r * 64 + d];
    } else if (r < 64) {
      v = Wk[(r - 32) * 64 + d];
    } else if (r < 96) {
      int rr = r - 64;
      float acc = 0.f;
      for (int m = 0; m < 32; ++m) acc += Wr[rr * 32 + m] * Wq[m * 64 + d];
      v = acc;
    } else {
      v = Wv[(r - 96) * 64 + d];
    }
    Wcat[i] = v;
  }
  if (t < 160) {
    int r = t;
    float v;
    if (r < 32) {
      v = bq[r];
    } else if (r < 64) {
      v = bk[r - 32];
    } else if (r < 96) {
      int rr = r - 64;
      float acc = br[rr];
      for (int m = 0; m < 32; ++m) acc += Wr[rr * 32 + m] * bq[m];
      v = acc;
    } else {
      v = bv[r - 96];
    }
    bcat[r] = v;
  }
}

// ----------------------------------------------------------------- main ----
__global__ __launch_bounds__(256, 2)
void policy_kernel(const float* __restrict__ x,
                   const float* __restrict__ Wcat,
                   const float* __restrict__ bcat,
                   const float* __restrict__ Wp1,
                   const float* __restrict__ bp1,
                   const float* __restrict__ Wp2,
                   const float* __restrict__ bp2,
                   const float* __restrict__ Wh1,
                   const float* __restrict__ bh1,
                   const float* __restrict__ Wh2,
                   const float* __restrict__ bh2,
                   float* __restrict__ out, int B) {
  // 32 batches/block = 160 agent-rows.
  __shared__ __align__(16) unsigned short Els[160 * ESTR];  // 51,840 B (bf16 E)
  __shared__ float maskLs[160];                             // 640 B
  __shared__ float asw[32 * 25];                            // 3,200 B  masked-A rows
  __shared__ float pooledLs[32 * 66];                       // 8,448 B  (stride 66)
  // Phase-3 aliases inside the (then-dead) E region:
  float* Hls = (float*)Els;                                           // [32][130] f32 = 16,640 B
  unsigned short* WmlpLs  = (unsigned short*)((char*)Els + 16640);    // [128][66] bf16 = 16,896 B
  unsigned short* WheadLs = (unsigned short*)((char*)Els + 33536);    // [51][66]  bf16 =  6,732 B

  const int t = threadIdx.x;

  // ---- phase 1: E = x_row @ Wcat^T + bcat, plus agent mask --------------
  if (t < 160) {
    const int r = t;
    const long grow = (long)blockIdx.x * 160 + r;       // global agent row
    const float4* xp = (const float4*)(x + grow * 64);  // 256 B, 16-aligned
    float xv[64];
    float msum = 0.f;
#pragma unroll
    for (int i = 0; i < 16; ++i) {
      float4 v = xp[i];
      xv[4 * i + 0] = v.x; xv[4 * i + 1] = v.y;
      xv[4 * i + 2] = v.z; xv[4 * i + 3] = v.w;
      msum += fabsf(v.x) + fabsf(v.y) + fabsf(v.z) + fabsf(v.w);
    }
    maskLs[r] = (msum > 0.01f) ? 1.f : 0.f;

    for (int c = 0; c < 160; c += 2) {   // c wave-uniform -> scalar weight loads
      const float* w0 = Wcat + c * 64;
      float e0x = 0.f, e0y = 0.f, e1x = 0.f, e1y = 0.f;
#pragma unroll
      for (int k = 0; k < 32; ++k) {
        e0x = __builtin_fmaf(xv[2 * k],     w0[2 * k],          e0x);
        e0y = __builtin_fmaf(xv[2 * k + 1], w0[2 * k + 1],      e0y);
        e1x = __builtin_fmaf(xv[2 * k],     w0[64 + 2 * k],     e1x);
        e1y = __builtin_fmaf(xv[2 * k + 1], w0[64 + 2 * k + 1], e1y);
      }
      float e0 = e0x + e0y + bcat[c];
      float e1 = e1x + e1y + bcat[c + 1];
      unsigned int pk = (unsigned int)f2b(e0) | ((unsigned int)f2b(e1) << 16);
      *(unsigned int*)&Els[r * ESTR + c] = pk;
    }
  }
  __syncthreads();

  // ---- phase 2: S = scale*(Q·K + R·R), softmax, mask --------------------
  if (t < 160) {
    const int b = t / 5, q = t - 5 * b;  // own row == t
    float qrv[64];  // [0:32)=own Q, [32:64)=own R
#pragma unroll
    for (int j = 0; j < 16; ++j) {
      unsigned int pk = *(const unsigned int*)&Els[t * ESTR + 2 * j];
      qrv[2 * j] = b2f_lo(pk); qrv[2 * j + 1] = b2f_hi(pk);
    }
#pragma unroll
    for (int j = 0; j < 16; ++j) {
      unsigned int pk = *(const unsigned int*)&Els[t * ESTR + 64 + 2 * j];
      qrv[32 + 2 * j] = b2f_lo(pk); qrv[33 + 2 * j] = b2f_hi(pk);
    }
    float sc[5];
#pragma unroll
    for (int k = 0; k < 5; ++k) {
      const unsigned short* er = &Els[(5 * b + k) * ESTR];
      float ax = 0.f, ay = 0.f;
#pragma unroll
      for (int j = 0; j < 16; ++j) {  // Q[q]·K[k]
        unsigned int pk = *(const unsigned int*)&er[32 + 2 * j];
        ax = __builtin_fmaf(qrv[2 * j],     b2f_lo(pk), ax);
        ay = __builtin_fmaf(qrv[2 * j + 1], b2f_hi(pk), ay);
      }
#pragma unroll
      for (int j = 0; j < 16; ++j) {  // R[q]·R[k]
        unsigned int pk = *(const unsigned int*)&er[64 + 2 * j];
        ax = __builtin_fmaf(qrv[32 + 2 * j], b2f_lo(pk), ax);
        ay = __builtin_fmaf(qrv[33 + 2 * j], b2f_hi(pk), ay);
      }
      sc[k] = (ax + ay) * 0.17677669529663689f;  // 1/sqrt(32)
    }
    float mx = sc[0];
#pragma unroll
    for (int k = 1; k < 5; ++k) mx = fmaxf(mx, sc[k]);
    float p[5], ps = 0.f;
#pragma unroll
    for (int k = 0; k < 5; ++k) { p[k] = __expf(sc[k] - mx); ps += p[k]; }
    float mscale = maskLs[t] / ps;  // mask[q] * softmax normalize
#pragma unroll
    for (int k = 0; k < 5; ++k) asw[b * 25 + q * 5 + k] = p[k] * mscale;
  }
  __syncthreads();

  // ---- phase 3a: pooled[b][d] = inv * sum_k w[k]*V[k][d] ----------------
  for (int i = t; i < 32 * 64; i += 256) {  // 8 iterations
    int b = i >> 6, d = i & 63;
    const float* aw = &asw[b * 25];
    float wk[5] = {0.f, 0.f, 0.f, 0.f, 0.f};
#pragma unroll
    for (int q2 = 0; q2 < 5; ++q2)
#pragma unroll
      for (int k = 0; k < 5; ++k) wk[k] += aw[q2 * 5 + k];
    float msumB = maskLs[b * 5] + maskLs[b * 5 + 1] + maskLs[b * 5 + 2] +
                  maskLs[b * 5 + 3] + maskLs[b * 5 + 4];
    float inv = 1.0f / (msumB + 1e-8f);
    float acc = 0.f;
#pragma unroll
    for (int k = 0; k < 5; ++k)
      acc += wk[k] * b2f(Els[(5 * b + k) * ESTR + 96 + d]);
    pooledLs[b * 66 + d] = acc * inv;
  }
  __syncthreads();

  // ---- stage MLP weights into LDS as bf16 (E region is dead now) --------
  for (int i = t; i < 128 * 64; i += 256) {
    int c = i >> 6, d = i & 63;
    float w = (c < 64) ? Wp1[c * 64 + d] : Wh1[(c - 64) * 64 + d];
    WmlpLs[c * 66 + d] = f2b(w);
  }
  for (int i = t; i < 51 * 64; i += 256) {
    int o = i >> 6, d = i & 63;
    float w = (o < 50) ? Wp2[o * 64 + d] : Wh2[d];
    WheadLs[o * 66 + d] = f2b(w);
  }
  __syncthreads();

  // ---- phase 3b: H[b][c] = gelu(pooled[b]·Wmlp[c] + bias) ---------------
  for (int i = t; i < 32 * 128; i += 256) {  // 16 iterations
    int b = i >> 7, c = i & 127;
    const unsigned short* wr = &WmlpLs[c * 66];
    const float* pv = &pooledLs[b * 66];
    float ax = 0.f, ay = 0.f;
#pragma unroll
    for (int j = 0; j < 32; ++j) {
      unsigned int pk = *(const unsigned int*)&wr[2 * j];
      ax = __builtin_fmaf(pv[2 * j],     b2f_lo(pk), ax);
      ay = __builtin_fmaf(pv[2 * j + 1], b2f_hi(pk), ay);
    }
    float v = ax + ay + ((c < 64) ? bp1[c] : bh1[c - 64]);
    float g = 0.5f * v * (1.0f + erff(v * 0.70710678118654752f));  // exact gelu
    Hls[b * 130 + c] = g;
  }
  __syncthreads();

  // ---- phase 3c: logits (50) + value (1) per batch ----------------------
  for (int i = t; i < 32 * 51; i += 256) {
    int b = i / 51, o = i - 51 * b;
    const float* hrow = &Hls[b * 130 + ((o < 50) ? 0 : 64)];
    const unsigned short* wr = &WheadLs[o * 66];
    float ax = 0.f, ay = 0.f;
#pragma unroll
    for (int j = 0; j < 32; ++j) {
      unsigned int pk = *(const unsigned int*)&wr[2 * j];
      ax = __builtin_fmaf(hrow[2 * j],     b2f_lo(pk), ax);
      ay = __builtin_fmaf(hrow[2 * j + 1], b2f_hi(pk), ay);
    }
    float v = ax + ay + ((o < 50) ? bp2[o] : bh2[0]);
    long gb = (long)blockIdx.x * 32 + b;
    if (o < 50) out[gb * 50 + o] = v;
    else        out[(long)B * 50 + gb] = v;
  }
}

// --------------------------------------------------------------- launch ----
extern "C" void kernel_launch(void* const* d_in, const int* in_sizes, int n_in,
                              void* d_out, int out_size, void* d_ws, size_t ws_size,
                              hipStream_t stream) {
  const float* x   = (const float*)d_in[0];
  const float* Wk  = (const float*)d_in[1];
  const float* bk  = (const float*)d_in[2];
  const float* Wq  = (const float*)d_in[3];
  const float* bq  = (const float*)d_in[4];
  const float* Wv  = (const float*)d_in[5];
  const float* bv  = (const float*)d_in[6];
  const float* Wr  = (const float*)d_in[7];
  const float* br  = (const float*)d_in[8];
  const float* Wp1 = (const float*)d_in[9];
  const float* bp1 = (const float*)d_in[10];
  const float* Wp2 = (const float*)d_in[11];
  const float* bp2 = (const float*)d_in[12];
  const float* Wh1 = (const float*)d_in[13];
  const float* bh1 = (const float*)d_in[14];
  const float* Wh2 = (const float*)d_in[15];
  const float* bh2 = (const float*)d_in[16];

  float* Wcat = (float*)d_ws;                          // 160*64 f32 = 40,960 B
  float* bcat = (float*)((char*)d_ws + 160 * 64 * 4);  // 160 f32

  int B = in_sizes[0] / 320;  // 131072

  setup_kernel<<<1, 256, 0, stream>>>(Wk, bk, Wq, bq, Wv, bv, Wr, br, Wcat, bcat);
  policy_kernel<<<B / 32, 256, 0, stream>>>(x, Wcat, bcat, Wp1, bp1, Wp2, bp2,
                                            Wh1, bh1, Wh2, bh2,
                                            (float*)d_out, B);
}

// Round 4
// 667.919 us; speedup vs baseline: 1.3403x; 1.3403x over previous
//
#include <hip/hip_runtime.h>
#include <stdint.h>

// LightMetaPolicy fused kernel, round 4: MFMA phase-1 with SPLIT-bf16 x
// (x = x_hi + x_lo, two bf16 MFMAs into one f32 acc -> f32-accurate x),
// phases 2/3 are the round-2 VALU code that passed at absmax 0.0156.
//
// Folds: R = x@(Wr@Wq)^T + (Wr@bq+br); pooled via column-sum of masked A.
// E LDS per agent-row: cols [0:32)=Q, [32:64)=K, [64:96)=R, [96:160)=V
//
// MFMA 16x16x32 bf16 layouts (m89-verified):
//   A: lane holds A[m=lane&15][k=quad*8+j], j=0..7  (quad=lane>>4)
//   B: lane holds B[k=quad*8+j][n=lane&15]
//   C: lane reg r holds C[row=quad*4+r][col=lane&15]
// Phase-1 weight B-fragments prestaged in ws fragment-linear:
//   frag[fs][lane][j] -> coalesced uint4 load at (fs*64+lane)*16 bytes.

typedef __attribute__((ext_vector_type(8))) short bf16x8;
typedef __attribute__((ext_vector_type(4))) float f32x4;

#define ESTR 162   // E stride (shorts): 81 dwords, odd -> conflict-free rows

#define WF1_OFF 0      // phase-1 B-frags: 20 frags * 64 lanes * 16B = 20480
#define BC_OFF  20480  // bcat f32[160]

__device__ __forceinline__ float b2f_lo(unsigned int pk) {
  union { unsigned int i; float f; } v; v.i = pk << 16; return v.f;
}
__device__ __forceinline__ float b2f_hi(unsigned int pk) {
  union { unsigned int i; float f; } v; v.i = pk & 0xffff0000u; return v.f;
}
__device__ __forceinline__ float b2f(unsigned short u) {
  union { unsigned int i; float f; } v; v.i = ((unsigned int)u) << 16; return v.f;
}
__device__ __forceinline__ unsigned short f2b(float f) {
  union { float f; unsigned int i; } v; v.f = f;
  unsigned int u = v.i;
  return (unsigned short)((u + 0x7fffu + ((u >> 16) & 1u)) >> 16);  // RNE
}

// ---------------------------------------------------------------- setup ----
__global__ void setup_kernel(const float* __restrict__ Wk,
                             const float* __restrict__ bk,
                             const float* __restrict__ Wq,
                             const float* __restrict__ bq,
                             const float* __restrict__ Wv,
                             const float* __restrict__ bv,
                             const float* __restrict__ Wr,
                             const float* __restrict__ br,
                             char* __restrict__ ws) {
  __shared__ float Wrp[32 * 64];  // Wr' = Wr @ Wq
  const int t = threadIdx.x;
  for (int i = t; i < 32 * 64; i += 256) {
    int rr = i >> 6, d = i & 63;
    float acc = 0.f;
    for (int m = 0; m < 32; ++m) acc += Wr[rr * 32 + m] * Wq[m * 64 + d];
    Wrp[i] = acc;
  }
  __syncthreads();

  unsigned short* wf1 = (unsigned short*)(ws + WF1_OFF);
  float* bc = (float*)(ws + BC_OFF);

  // phase-1 B-frags: fs = nt*2+s (nt 0..9, s 0..1)
  for (int i = t; i < 20 * 64 * 8; i += 256) {
    int j = i & 7, l = (i >> 3) & 63, fs = i >> 9;
    int nt = fs >> 1, s = fs & 1;
    int r = nt * 16 + (l & 15);            // output channel (Wcat row)
    int k = s * 32 + ((l >> 4) & 3) * 8 + j;
    float w;
    if (r < 32)      w = Wq[r * 64 + k];
    else if (r < 64) w = Wk[(r - 32) * 64 + k];
    else if (r < 96) w = Wrp[(r - 64) * 64 + k];
    else             w = Wv[(r - 96) * 64 + k];
    wf1[i] = f2b(w);
  }
  if (t < 160) {
    int r = t;
    float v;
    if (r < 32)      v = bq[r];
    else if (r < 64) v = bk[r - 32];
    else if (r < 96) {
      int rr = r - 64;
      float acc = br[rr];
      for (int m = 0; m < 32; ++m) acc += Wr[rr * 32 + m] * bq[m];
      v = acc;
    } else            v = bv[r - 96];
    bc[r] = v;
  }
}

// ----------------------------------------------------------------- main ----
__global__ __launch_bounds__(256, 2)
void policy_kernel(const float* __restrict__ x,
                   const char* __restrict__ ws,
                   const float* __restrict__ Wp1,
                   const float* __restrict__ bp1,
                   const float* __restrict__ Wp2,
                   const float* __restrict__ bp2,
                   const float* __restrict__ Wh1,
                   const float* __restrict__ bh1,
                   const float* __restrict__ Wh2,
                   const float* __restrict__ bh2,
                   float* __restrict__ out, int B) {
  // 32 batches/block = 160 agent-rows.
  __shared__ __align__(16) unsigned short Els[160 * ESTR];  // 51,840 B
  __shared__ float maskLs[160];                             // 640 B
  __shared__ float asw[32 * 25];                            // 3,200 B
  __shared__ float pooledLs[32 * 66];                       // 8,448 B
  // Phase-3 aliases inside the (then-dead) E region:
  float* Hls = (float*)Els;                                           // [32][130] f32
  unsigned short* WmlpLs  = (unsigned short*)((char*)Els + 16640);    // [128][66] bf16
  unsigned short* WheadLs = (unsigned short*)((char*)Els + 33536);    // [51][66]  bf16

  const int t = threadIdx.x;
  const int w = t >> 6, lane = t & 63;
  const int l15 = lane & 15, quad = lane >> 4;

  const uint4* wf1 = (const uint4*)(ws + WF1_OFF);
  const float* bc = (const float*)(ws + BC_OFF);

  // ---- phase 0: agent mask (also pre-warms the x tile in L1/L2) ---------
  if (t < 160) {
    long row = (long)blockIdx.x * 160 + t;
    const float4* xp = (const float4*)(x + row * 64);
    float ms = 0.f;
#pragma unroll
    for (int i = 0; i < 16; ++i) {
      float4 v = xp[i];
      ms += fabsf(v.x) + fabsf(v.y) + fabsf(v.z) + fabsf(v.w);
    }
    maskLs[t] = (ms > 0.01f) ? 1.f : 0.f;
  }

  // ---- phase 1: E = x @ Wcat^T + bcat via MFMA, split-bf16 x ------------
  {
    uint4 barr[20];
#pragma unroll
    for (int f = 0; f < 20; ++f) barr[f] = wf1[f * 64 + lane];
    float bcal[10];
#pragma unroll
    for (int n = 0; n < 10; ++n) bcal[n] = bc[n * 16 + l15];

    union { uint4 u; bf16x8 v; } ah0, ah1, al0, al1;  // hi/lo x k-halves
    int mcur = -1;
    for (int ti = 0; ti < 25; ++ti) {
      int tt = w * 25 + ti;
      int m = tt / 10, n = tt - m * 10;
      if (m != mcur) {
        mcur = m;
        long row = (long)blockIdx.x * 160 + m * 16 + l15;
        const float* xr = x + row * 64 + quad * 8;
        float xv[16];
        *(float4*)(xv + 0)  = *(const float4*)(xr);
        *(float4*)(xv + 4)  = *(const float4*)(xr + 4);
        *(float4*)(xv + 8)  = *(const float4*)(xr + 32);
        *(float4*)(xv + 12) = *(const float4*)(xr + 36);
        unsigned int hw[8], lw[8];
#pragma unroll
        for (int i = 0; i < 8; ++i) {
          unsigned short h0 = f2b(xv[2 * i]);
          unsigned short h1 = f2b(xv[2 * i + 1]);
          float r0 = xv[2 * i]     - b2f(h0);
          float r1 = xv[2 * i + 1] - b2f(h1);
          hw[i] = (unsigned int)h0 | ((unsigned int)h1 << 16);
          lw[i] = (unsigned int)f2b(r0) | ((unsigned int)f2b(r1) << 16);
        }
        ah0.u = make_uint4(hw[0], hw[1], hw[2], hw[3]);
        ah1.u = make_uint4(hw[4], hw[5], hw[6], hw[7]);
        al0.u = make_uint4(lw[0], lw[1], lw[2], lw[3]);
        al1.u = make_uint4(lw[4], lw[5], lw[6], lw[7]);
      }
      union { uint4 u; bf16x8 v; } b0, b1;
      b0.u = barr[n * 2 + 0];
      b1.u = barr[n * 2 + 1];
      f32x4 acc = {0.f, 0.f, 0.f, 0.f};
      acc = __builtin_amdgcn_mfma_f32_16x16x32_bf16(al0.v, b0.v, acc, 0, 0, 0);
      acc = __builtin_amdgcn_mfma_f32_16x16x32_bf16(al1.v, b1.v, acc, 0, 0, 0);
      acc = __builtin_amdgcn_mfma_f32_16x16x32_bf16(ah0.v, b0.v, acc, 0, 0, 0);
      acc = __builtin_amdgcn_mfma_f32_16x16x32_bf16(ah1.v, b1.v, acc, 0, 0, 0);
      float bias = bcal[n];
      int r0 = m * 16 + quad * 4;
      int col = n * 16 + l15;
#pragma unroll
      for (int r = 0; r < 4; ++r)
        Els[(r0 + r) * ESTR + col] = f2b(acc[r] + bias);
    }
  }
  __syncthreads();

  // ---- phase 2: S = scale*(Q·K + R·R), softmax, mask (round-2 code) -----
  if (t < 160) {
    const int b = t / 5, q = t - 5 * b;
    float qrv[64];
#pragma unroll
    for (int j = 0; j < 16; ++j) {
      unsigned int pk = *(const unsigned int*)&Els[t * ESTR + 2 * j];
      qrv[2 * j] = b2f_lo(pk); qrv[2 * j + 1] = b2f_hi(pk);
    }
#pragma unroll
    for (int j = 0; j < 16; ++j) {
      unsigned int pk = *(const unsigned int*)&Els[t * ESTR + 64 + 2 * j];
      qrv[32 + 2 * j] = b2f_lo(pk); qrv[33 + 2 * j] = b2f_hi(pk);
    }
    float sc[5];
#pragma unroll
    for (int k = 0; k < 5; ++k) {
      const unsigned short* er = &Els[(5 * b + k) * ESTR];
      float ax = 0.f, ay = 0.f;
#pragma unroll
      for (int j = 0; j < 16; ++j) {
        unsigned int pk = *(const unsigned int*)&er[32 + 2 * j];
        ax = __builtin_fmaf(qrv[2 * j],     b2f_lo(pk), ax);
        ay = __builtin_fmaf(qrv[2 * j + 1], b2f_hi(pk), ay);
      }
#pragma unroll
      for (int j = 0; j < 16; ++j) {
        unsigned int pk = *(const unsigned int*)&er[64 + 2 * j];
        ax = __builtin_fmaf(qrv[32 + 2 * j], b2f_lo(pk), ax);
        ay = __builtin_fmaf(qrv[33 + 2 * j], b2f_hi(pk), ay);
      }
      sc[k] = (ax + ay) * 0.17677669529663689f;
    }
    float mx = sc[0];
#pragma unroll
    for (int k = 1; k < 5; ++k) mx = fmaxf(mx, sc[k]);
    float p[5], ps = 0.f;
#pragma unroll
    for (int k = 0; k < 5; ++k) { p[k] = __expf(sc[k] - mx); ps += p[k]; }
    float mscale = maskLs[t] / ps;
#pragma unroll
    for (int k = 0; k < 5; ++k) asw[b * 25 + q * 5 + k] = p[k] * mscale;
  }
  __syncthreads();

  // ---- phase 3a: pooled[b][d] = inv * sum_k w[k]*V[k][d] ----------------
  for (int i = t; i < 32 * 64; i += 256) {
    int b = i >> 6, d = i & 63;
    const float* aw = &asw[b * 25];
    float wk[5] = {0.f, 0.f, 0.f, 0.f, 0.f};
#pragma unroll
    for (int q2 = 0; q2 < 5; ++q2)
#pragma unroll
      for (int k = 0; k < 5; ++k) wk[k] += aw[q2 * 5 + k];
    float msumB = maskLs[b * 5] + maskLs[b * 5 + 1] + maskLs[b * 5 + 2] +
                  maskLs[b * 5 + 3] + maskLs[b * 5 + 4];
    float inv = 1.0f / (msumB + 1e-8f);
    float acc = 0.f;
#pragma unroll
    for (int k = 0; k < 5; ++k)
      acc += wk[k] * b2f(Els[(5 * b + k) * ESTR + 96 + d]);
    pooledLs[b * 66 + d] = acc * inv;
  }
  __syncthreads();

  // ---- stage MLP weights into LDS as bf16 (E region is dead now) --------
  for (int i = t; i < 128 * 64; i += 256) {
    int c = i >> 6, d = i & 63;
    float wv = (c < 64) ? Wp1[c * 64 + d] : Wh1[(c - 64) * 64 + d];
    WmlpLs[c * 66 + d] = f2b(wv);
  }
  for (int i = t; i < 51 * 64; i += 256) {
    int o = i >> 6, d = i & 63;
    float wv = (o < 50) ? Wp2[o * 64 + d] : Wh2[d];
    WheadLs[o * 66 + d] = f2b(wv);
  }
  __syncthreads();

  // ---- phase 3b: H[b][c] = gelu(pooled[b]·Wmlp[c] + bias) ---------------
  for (int i = t; i < 32 * 128; i += 256) {
    int b = i >> 7, c = i & 127;
    const unsigned short* wr = &WmlpLs[c * 66];
    const float* pv = &pooledLs[b * 66];
    float ax = 0.f, ay = 0.f;
#pragma unroll
    for (int j = 0; j < 32; ++j) {
      unsigned int pk = *(const unsigned int*)&wr[2 * j];
      ax = __builtin_fmaf(pv[2 * j],     b2f_lo(pk), ax);
      ay = __builtin_fmaf(pv[2 * j + 1], b2f_hi(pk), ay);
    }
    float v = ax + ay + ((c < 64) ? bp1[c] : bh1[c - 64]);
    float g = 0.5f * v * (1.0f + erff(v * 0.70710678118654752f));  // exact gelu
    Hls[b * 130 + c] = g;
  }
  __syncthreads();

  // ---- phase 3c: logits (50) + value (1) per batch ----------------------
  for (int i = t; i < 32 * 51; i += 256) {
    int b = i / 51, o = i - 51 * b;
    const float* hrow = &Hls[b * 130 + ((o < 50) ? 0 : 64)];
    const unsigned short* wr = &WheadLs[o * 66];
    float ax = 0.f, ay = 0.f;
#pragma unroll
    for (int j = 0; j < 32; ++j) {
      unsigned int pk = *(const unsigned int*)&wr[2 * j];
      ax = __builtin_fmaf(hrow[2 * j],     b2f_lo(pk), ax);
      ay = __builtin_fmaf(hrow[2 * j + 1], b2f_hi(pk), ay);
    }
    float v = ax + ay + ((o < 50) ? bp2[o] : bh2[0]);
    long gb = (long)blockIdx.x * 32 + b;
    if (o < 50) out[gb * 50 + o] = v;
    else        out[(long)B * 50 + gb] = v;
  }
}

// --------------------------------------------------------------- launch ----
extern "C" void kernel_launch(void* const* d_in, const int* in_sizes, int n_in,
                              void* d_out, int out_size, void* d_ws, size_t ws_size,
                              hipStream_t stream) {
  const float* x   = (const float*)d_in[0];
  const float* Wk  = (const float*)d_in[1];
  const float* bk  = (const float*)d_in[2];
  const float* Wq  = (const float*)d_in[3];
  const float* bq  = (const float*)d_in[4];
  const float* Wv  = (const float*)d_in[5];
  const float* bv  = (const float*)d_in[6];
  const float* Wr  = (const float*)d_in[7];
  const float* br  = (const float*)d_in[8];
  const float* Wp1 = (const float*)d_in[9];
  const float* bp1 = (const float*)d_in[10];
  const float* Wp2 = (const float*)d_in[11];
  const float* bp2 = (const float*)d_in[12];
  const float* Wh1 = (const float*)d_in[13];
  const float* bh1 = (const float*)d_in[14];
  const float* Wh2 = (const float*)d_in[15];
  const float* bh2 = (const float*)d_in[16];

  int B = in_sizes[0] / 320;  // 131072

  setup_kernel<<<1, 256, 0, stream>>>(Wk, bk, Wq, bq, Wv, bv, Wr, br,
                                      (char*)d_ws);
  policy_kernel<<<B / 32, 256, 0, stream>>>(x, (const char*)d_ws,
                                            Wp1, bp1, Wp2, bp2,
                                            Wh1, bh1, Wh2, bh2,
                                            (float*)d_out, B);
}

// Round 5
// 518.345 us; speedup vs baseline: 1.7270x; 1.2886x over previous
//
#include <hip/hip_runtime.h>
#include <stdint.h>

// LightMetaPolicy fused kernel, round 5: round-4 structure (MFMA phase-1 with
// split-bf16 x) minus the VGPR-spilling B-fragment register cache. B-frags are
// re-loaded from ws inside the loop (20 KB table -> L1-resident).
//
// Folds: R = x@(Wr@Wq)^T + (Wr@bq+br); pooled via column-sum of masked A.
// E LDS per agent-row: cols [0:32)=Q, [32:64)=K, [64:96)=R, [96:160)=V
//
// MFMA 16x16x32 bf16 layouts (m89-verified):
//   A: lane holds A[m=lane&15][k=quad*8+j], j=0..7  (quad=lane>>4)
//   B: lane holds B[k=quad*8+j][n=lane&15]
//   C: lane reg r holds C[row=quad*4+r][col=lane&15]

typedef __attribute__((ext_vector_type(8))) short bf16x8;
typedef __attribute__((ext_vector_type(4))) float f32x4;

#define ESTR 162   // E stride (shorts): 81 dwords, odd -> conflict-free rows

#define WF1_OFF 0      // phase-1 B-frags: 20 frags * 64 lanes * 16B = 20480
#define BC_OFF  20480  // bcat f32[160]

__device__ __forceinline__ float b2f_lo(unsigned int pk) {
  union { unsigned int i; float f; } v; v.i = pk << 16; return v.f;
}
__device__ __forceinline__ float b2f_hi(unsigned int pk) {
  union { unsigned int i; float f; } v; v.i = pk & 0xffff0000u; return v.f;
}
__device__ __forceinline__ float b2f(unsigned short u) {
  union { unsigned int i; float f; } v; v.i = ((unsigned int)u) << 16; return v.f;
}
__device__ __forceinline__ unsigned short f2b(float f) {
  union { float f; unsigned int i; } v; v.f = f;
  unsigned int u = v.i;
  return (unsigned short)((u + 0x7fffu + ((u >> 16) & 1u)) >> 16);  // RNE
}

// ---------------------------------------------------------------- setup ----
__global__ void setup_kernel(const float* __restrict__ Wk,
                             const float* __restrict__ bk,
                             const float* __restrict__ Wq,
                             const float* __restrict__ bq,
                             const float* __restrict__ Wv,
                             const float* __restrict__ bv,
                             const float* __restrict__ Wr,
                             const float* __restrict__ br,
                             char* __restrict__ ws) {
  __shared__ float Wrp[32 * 64];  // Wr' = Wr @ Wq
  const int t = threadIdx.x;
  for (int i = t; i < 32 * 64; i += 256) {
    int rr = i >> 6, d = i & 63;
    float acc = 0.f;
    for (int m = 0; m < 32; ++m) acc += Wr[rr * 32 + m] * Wq[m * 64 + d];
    Wrp[i] = acc;
  }
  __syncthreads();

  unsigned short* wf1 = (unsigned short*)(ws + WF1_OFF);
  float* bc = (float*)(ws + BC_OFF);

  // phase-1 B-frags: fs = nt*2+s (nt 0..9, s 0..1)
  for (int i = t; i < 20 * 64 * 8; i += 256) {
    int j = i & 7, l = (i >> 3) & 63, fs = i >> 9;
    int nt = fs >> 1, s = fs & 1;
    int r = nt * 16 + (l & 15);            // output channel (Wcat row)
    int k = s * 32 + ((l >> 4) & 3) * 8 + j;
    float w;
    if (r < 32)      w = Wq[r * 64 + k];
    else if (r < 64) w = Wk[(r - 32) * 64 + k];
    else if (r < 96) w = Wrp[(r - 64) * 64 + k];
    else             w = Wv[(r - 96) * 64 + k];
    wf1[i] = f2b(w);
  }
  if (t < 160) {
    int r = t;
    float v;
    if (r < 32)      v = bq[r];
    else if (r < 64) v = bk[r - 32];
    else if (r < 96) {
      int rr = r - 64;
      float acc = br[rr];
      for (int m = 0; m < 32; ++m) acc += Wr[rr * 32 + m] * bq[m];
      v = acc;
    } else            v = bv[r - 96];
    bc[r] = v;
  }
}

// ----------------------------------------------------------------- main ----
__global__ __launch_bounds__(256, 2)
void policy_kernel(const float* __restrict__ x,
                   const char* __restrict__ ws,
                   const float* __restrict__ Wp1,
                   const float* __restrict__ bp1,
                   const float* __restrict__ Wp2,
                   const float* __restrict__ bp2,
                   const float* __restrict__ Wh1,
                   const float* __restrict__ bh1,
                   const float* __restrict__ Wh2,
                   const float* __restrict__ bh2,
                   float* __restrict__ out, int B) {
  // 32 batches/block = 160 agent-rows.
  __shared__ __align__(16) unsigned short Els[160 * ESTR];  // 51,840 B
  __shared__ float maskLs[160];                             // 640 B
  __shared__ float asw[32 * 25];                            // 3,200 B
  __shared__ float pooledLs[32 * 66];                       // 8,448 B
  // Phase-3 aliases inside the (then-dead) E region:
  float* Hls = (float*)Els;                                           // [32][130] f32
  unsigned short* WmlpLs  = (unsigned short*)((char*)Els + 16640);    // [128][66] bf16
  unsigned short* WheadLs = (unsigned short*)((char*)Els + 33536);    // [51][66]  bf16

  const int t = threadIdx.x;
  const int w = t >> 6, lane = t & 63;
  const int l15 = lane & 15, quad = lane >> 4;

  const uint4* wf1 = (const uint4*)(ws + WF1_OFF);
  const float* bc = (const float*)(ws + BC_OFF);

  // ---- phase 0: agent mask (also pre-warms the x tile in L1/L2) ---------
  if (t < 160) {
    long row = (long)blockIdx.x * 160 + t;
    const float4* xp = (const float4*)(x + row * 64);
    float ms = 0.f;
#pragma unroll
    for (int i = 0; i < 16; ++i) {
      float4 v = xp[i];
      ms += fabsf(v.x) + fabsf(v.y) + fabsf(v.z) + fabsf(v.w);
    }
    maskLs[t] = (ms > 0.01f) ? 1.f : 0.f;
  }

  // ---- phase 1: E = x @ Wcat^T + bcat via MFMA, split-bf16 x ------------
  // B-frags loaded from ws per-iteration (L1-resident 20 KB table) -- no
  // register cache, no spills (round-4 lesson: barr[20] = 80 VGPRs spilled
  // to scratch -> 380 MB of HBM spill traffic).
  {
    union { uint4 u; bf16x8 v; } ah0, ah1, al0, al1;  // hi/lo x k-halves
    int mcur = -1;
    for (int ti = 0; ti < 25; ++ti) {
      int tt = w * 25 + ti;
      int m = tt / 10, n = tt - m * 10;
      if (m != mcur) {
        mcur = m;
        long row = (long)blockIdx.x * 160 + m * 16 + l15;
        const float* xr = x + row * 64 + quad * 8;
        float xv[16];
        *(float4*)(xv + 0)  = *(const float4*)(xr);
        *(float4*)(xv + 4)  = *(const float4*)(xr + 4);
        *(float4*)(xv + 8)  = *(const float4*)(xr + 32);
        *(float4*)(xv + 12) = *(const float4*)(xr + 36);
        unsigned int hw[8], lw[8];
#pragma unroll
        for (int i = 0; i < 8; ++i) {
          unsigned short h0 = f2b(xv[2 * i]);
          unsigned short h1 = f2b(xv[2 * i + 1]);
          float r0 = xv[2 * i]     - b2f(h0);
          float r1 = xv[2 * i + 1] - b2f(h1);
          hw[i] = (unsigned int)h0 | ((unsigned int)h1 << 16);
          lw[i] = (unsigned int)f2b(r0) | ((unsigned int)f2b(r1) << 16);
        }
        ah0.u = make_uint4(hw[0], hw[1], hw[2], hw[3]);
        ah1.u = make_uint4(hw[4], hw[5], hw[6], hw[7]);
        al0.u = make_uint4(lw[0], lw[1], lw[2], lw[3]);
        al1.u = make_uint4(lw[4], lw[5], lw[6], lw[7]);
      }
      union { uint4 u; bf16x8 v; } b0, b1;
      b0.u = wf1[(n * 2 + 0) * 64 + lane];
      b1.u = wf1[(n * 2 + 1) * 64 + lane];
      f32x4 acc = {0.f, 0.f, 0.f, 0.f};
      acc = __builtin_amdgcn_mfma_f32_16x16x32_bf16(al0.v, b0.v, acc, 0, 0, 0);
      acc = __builtin_amdgcn_mfma_f32_16x16x32_bf16(al1.v, b1.v, acc, 0, 0, 0);
      acc = __builtin_amdgcn_mfma_f32_16x16x32_bf16(ah0.v, b0.v, acc, 0, 0, 0);
      acc = __builtin_amdgcn_mfma_f32_16x16x32_bf16(ah1.v, b1.v, acc, 0, 0, 0);
      float bias = bc[n * 16 + l15];
      int r0 = m * 16 + quad * 4;
      int col = n * 16 + l15;
#pragma unroll
      for (int r = 0; r < 4; ++r)
        Els[(r0 + r) * ESTR + col] = f2b(acc[r] + bias);
    }
  }
  __syncthreads();

  // ---- phase 2: S = scale*(Q·K + R·R), softmax, mask (round-2 code) -----
  if (t < 160) {
    const int b = t / 5, q = t - 5 * b;
    float qrv[64];
#pragma unroll
    for (int j = 0; j < 16; ++j) {
      unsigned int pk = *(const unsigned int*)&Els[t * ESTR + 2 * j];
      qrv[2 * j] = b2f_lo(pk); qrv[2 * j + 1] = b2f_hi(pk);
    }
#pragma unroll
    for (int j = 0; j < 16; ++j) {
      unsigned int pk = *(const unsigned int*)&Els[t * ESTR + 64 + 2 * j];
      qrv[32 + 2 * j] = b2f_lo(pk); qrv[33 + 2 * j] = b2f_hi(pk);
    }
    float sc[5];
#pragma unroll
    for (int k = 0; k < 5; ++k) {
      const unsigned short* er = &Els[(5 * b + k) * ESTR];
      float ax = 0.f, ay = 0.f;
#pragma unroll
      for (int j = 0; j < 16; ++j) {
        unsigned int pk = *(const unsigned int*)&er[32 + 2 * j];
        ax = __builtin_fmaf(qrv[2 * j],     b2f_lo(pk), ax);
        ay = __builtin_fmaf(qrv[2 * j + 1], b2f_hi(pk), ay);
      }
#pragma unroll
      for (int j = 0; j < 16; ++j) {
        unsigned int pk = *(const unsigned int*)&er[64 + 2 * j];
        ax = __builtin_fmaf(qrv[32 + 2 * j], b2f_lo(pk), ax);
        ay = __builtin_fmaf(qrv[33 + 2 * j], b2f_hi(pk), ay);
      }
      sc[k] = (ax + ay) * 0.17677669529663689f;
    }
    float mx = sc[0];
#pragma unroll
    for (int k = 1; k < 5; ++k) mx = fmaxf(mx, sc[k]);
    float p[5], ps = 0.f;
#pragma unroll
    for (int k = 0; k < 5; ++k) { p[k] = __expf(sc[k] - mx); ps += p[k]; }
    float mscale = maskLs[t] / ps;
#pragma unroll
    for (int k = 0; k < 5; ++k) asw[b * 25 + q * 5 + k] = p[k] * mscale;
  }
  __syncthreads();

  // ---- phase 3a: pooled[b][d] = inv * sum_k w[k]*V[k][d] ----------------
  for (int i = t; i < 32 * 64; i += 256) {
    int b = i >> 6, d = i & 63;
    const float* aw = &asw[b * 25];
    float wk[5] = {0.f, 0.f, 0.f, 0.f, 0.f};
#pragma unroll
    for (int q2 = 0; q2 < 5; ++q2)
#pragma unroll
      for (int k = 0; k < 5; ++k) wk[k] += aw[q2 * 5 + k];
    float msumB = maskLs[b * 5] + maskLs[b * 5 + 1] + maskLs[b * 5 + 2] +
                  maskLs[b * 5 + 3] + maskLs[b * 5 + 4];
    float inv = 1.0f / (msumB + 1e-8f);
    float acc = 0.f;
#pragma unroll
    for (int k = 0; k < 5; ++k)
      acc += wk[k] * b2f(Els[(5 * b + k) * ESTR + 96 + d]);
    pooledLs[b * 66 + d] = acc * inv;
  }
  __syncthreads();

  // ---- stage MLP weights into LDS as bf16 (E region is dead now) --------
  for (int i = t; i < 128 * 64; i += 256) {
    int c = i >> 6, d = i & 63;
    float wv = (c < 64) ? Wp1[c * 64 + d] : Wh1[(c - 64) * 64 + d];
    WmlpLs[c * 66 + d] = f2b(wv);
  }
  for (int i = t; i < 51 * 64; i += 256) {
    int o = i >> 6, d = i & 63;
    float wv = (o < 50) ? Wp2[o * 64 + d] : Wh2[d];
    WheadLs[o * 66 + d] = f2b(wv);
  }
  __syncthreads();

  // ---- phase 3b: H[b][c] = gelu(pooled[b]·Wmlp[c] + bias) ---------------
  for (int i = t; i < 32 * 128; i += 256) {
    int b = i >> 7, c = i & 127;
    const unsigned short* wr = &WmlpLs[c * 66];
    const float* pv = &pooledLs[b * 66];
    float ax = 0.f, ay = 0.f;
#pragma unroll
    for (int j = 0; j < 32; ++j) {
      unsigned int pk = *(const unsigned int*)&wr[2 * j];
      ax = __builtin_fmaf(pv[2 * j],     b2f_lo(pk), ax);
      ay = __builtin_fmaf(pv[2 * j + 1], b2f_hi(pk), ay);
    }
    float v = ax + ay + ((c < 64) ? bp1[c] : bh1[c - 64]);
    float g = 0.5f * v * (1.0f + erff(v * 0.70710678118654752f));  // exact gelu
    Hls[b * 130 + c] = g;
  }
  __syncthreads();

  // ---- phase 3c: logits (50) + value (1) per batch ----------------------
  for (int i = t; i < 32 * 51; i += 256) {
    int b = i / 51, o = i - 51 * b;
    const float* hrow = &Hls[b * 130 + ((o < 50) ? 0 : 64)];
    const unsigned short* wr = &WheadLs[o * 66];
    float ax = 0.f, ay = 0.f;
#pragma unroll
    for (int j = 0; j < 32; ++j) {
      unsigned int pk = *(const unsigned int*)&wr[2 * j];
      ax = __builtin_fmaf(hrow[2 * j],     b2f_lo(pk), ax);
      ay = __builtin_fmaf(hrow[2 * j + 1], b2f_hi(pk), ay);
    }
    float v = ax + ay + ((o < 50) ? bp2[o] : bh2[0]);
    long gb = (long)blockIdx.x * 32 + b;
    if (o < 50) out[gb * 50 + o] = v;
    else        out[(long)B * 50 + gb] = v;
  }
}

// --------------------------------------------------------------- launch ----
extern "C" void kernel_launch(void* const* d_in, const int* in_sizes, int n_in,
                              void* d_out, int out_size, void* d_ws, size_t ws_size,
                              hipStream_t stream) {
  const float* x   = (const float*)d_in[0];
  const float* Wk  = (const float*)d_in[1];
  const float* bk  = (const float*)d_in[2];
  const float* Wq  = (const float*)d_in[3];
  const float* bq  = (const float*)d_in[4];
  const float* Wv  = (const float*)d_in[5];
  const float* bv  = (const float*)d_in[6];
  const float* Wr  = (const float*)d_in[7];
  const float* br  = (const float*)d_in[8];
  const float* Wp1 = (const float*)d_in[9];
  const float* bp1 = (const float*)d_in[10];
  const float* Wp2 = (const float*)d_in[11];
  const float* bp2 = (const float*)d_in[12];
  const float* Wh1 = (const float*)d_in[13];
  const float* bh1 = (const float*)d_in[14];
  const float* Wh2 = (const float*)d_in[15];
  const float* bh2 = (const float*)d_in[16];

  int B = in_sizes[0] / 320;  // 131072

  setup_kernel<<<1, 256, 0, stream>>>(Wk, bk, Wq, bq, Wv, bv, Wr, br,
                                      (char*)d_ws);
  policy_kernel<<<B / 32, 256, 0, stream>>>(x, (const char*)d_ws,
                                            Wp1, bp1, Wp2, bp2,
                                            Wh1, bh1, Wh2, bh2,
                                            (float*)d_out, B);
}